// Round 3
// baseline (396.234 us; speedup 1.0000x reference)
//
#include <hip/hip_runtime.h>
#include <hip/hip_bf16.h>

// DIAGNOSTIC ROUND: identical kernel to R1, but launched 3x.
// Purpose: dur_us = harness_overhead + N*K. Our kernel never makes rocprof's
// top-5 (all slots are the harness's 1 GiB 0xAA poison fills @ ~165 us), so
// K is unobservable directly; Delta(dur)/2 measures it. Idempotent: all three
// launches write identical values, so validation and graph capture are fine.

#define NF 10          // NUM_FEATURES
#define EMB 256        // EMBED_DIM
#define TOK (256*512)  // B*S = 131072 tokens
#define OUTW 512       // 2*EMBED_DIM per token

__global__ __launch_bounds__(256) void bert_embed_kernel(
    const float* __restrict__ x,    // [TOK, NF]
    const int*   __restrict__ doy,  // [TOK]
    const float* __restrict__ W,    // [EMB, NF]
    const float* __restrict__ bias, // [EMB]
    float*       __restrict__ out)  // [TOK, OUTW]
{
    const int t          = threadIdx.x;
    const int tok_in_blk = t >> 7;    // 0 or 1
    const int q          = t & 127;   // quad index within token
    const bool is_obs    = (q < 64);  // uniform per wave

    // ---- per-thread loop-invariant state ----
    float w[4][NF];
    float bv[4];
    float dv0 = 0.f, dv1 = 0.f;
    if (is_obs) {
        const int e0 = q * 4;
        #pragma unroll
        for (int r = 0; r < 4; ++r) {
            #pragma unroll
            for (int f = 0; f < NF; ++f) w[r][f] = W[(e0 + r) * NF + f];
            bv[r] = bias[e0 + r];
        }
    } else {
        const int e0 = (q - 64) * 4;  // even element base
        const float c = -9.210340371976184f / 256.0f;  // -ln(10000)/EMBED_DIM
        dv0 = __expf((float)e0 * c);
        dv1 = __expf((float)(e0 + 2) * c);
    }

    const int stride = gridDim.x * 2;
    for (int tok = blockIdx.x * 2 + tok_in_blk; tok < TOK; tok += stride) {
        float4 o;
        if (is_obs) {
            const float* xp = x + (long long)tok * NF;
            float xv[NF];
            #pragma unroll
            for (int f = 0; f < NF; ++f) xv[f] = xp[f];
            #pragma unroll
            for (int r = 0; r < 4; ++r) {
                float acc = bv[r];
                #pragma unroll
                for (int f = 0; f < NF; ++f) acc = fmaf(w[r][f], xv[f], acc);
                (&o.x)[r] = acc;
            }
            *(float4*)(out + (long long)tok * OUTW + q * 4) = o;
        } else {
            const int d = doy[tok];           // wave-uniform
            if (d == 0) {
                o = make_float4(0.f, 0.f, 0.f, 0.f);  // pe row 0 is zeros
            } else {
                const float pos = (float)(d - 1);
                const float a0 = pos * dv0;
                const float a1 = pos * dv1;
                o.x = __sinf(a0); o.y = __cosf(a0);
                o.z = __sinf(a1); o.w = __cosf(a1);
            }
            *(float4*)(out + (long long)tok * OUTW + EMB + (q - 64) * 4) = o;
        }
    }
}

extern "C" void kernel_launch(void* const* d_in, const int* in_sizes, int n_in,
                              void* d_out, int out_size, void* d_ws, size_t ws_size,
                              hipStream_t stream) {
    const float* x    = (const float*)d_in[0];  // input_sequence [B,S,NF] fp32
    const int*   doy  = (const int*)  d_in[1];  // doy_sequence   [B,S]    int32
    const float* W    = (const float*)d_in[2];  // W [EMB,NF] fp32
    const float* bias = (const float*)d_in[3];  // b [EMB]    fp32
    float*       out  = (float*)d_out;          // [B,S,2*EMB] fp32

    // 3 identical launches: Delta(dur_us)/2 vs the single-launch baseline
    // (298.7 us) measures the kernel's true duration K.
    bert_embed_kernel<<<2048, 256, 0, stream>>>(x, doy, W, bias, out);
    bert_embed_kernel<<<2048, 256, 0, stream>>>(x, doy, W, bias, out);
    bert_embed_kernel<<<2048, 256, 0, stream>>>(x, doy, W, bias, out);
}